// Round 6
// baseline (37.587 us; speedup 1.0000x reference)
//
#include <hip/hip_runtime.h>
#include <hip/hip_bf16.h>

// loss_separation: X[n, b*2+c] = keypoints[b, n, c], N=8192 rows, K=128 cols.
// loss = sum_{i != j} exp(-0.4 * ||X_i - X_j||)
// Round 6 structure: 512 blocks x 4-5 consecutive upper-tri 128x128 tiles.
//   A row-panel fragments in VGPRs (reloaded only on row change);
//   B tiles double-buffered in LDS via global_load_lds(16B), 2-phase
//   pipeline: STAGE(next) -> ds_read+MFMA+epilogue(cur) -> barrier.
//   Per-wave running sum across steps; one partial store per block.

#define N_KP   8192
#define KDIM   128          // B*C = 64*2
#define NT     64           // number of 128-row tiles
#define NTILES (NT * (NT + 1) / 2)   // 2080 upper-tri tiles
#define NBLK   512
#define COEF2  (-0.57707801635558535f)   // -0.4 * log2(e)

typedef __attribute__((ext_vector_type(8))) short bf16x8;
typedef __attribute__((ext_vector_type(4))) float f32x4;

// Swizzled X layout (ushort units): fragment f = (rowblk16*4 + kk) holds the
// MFMA A/B fragment for rows [rowblk16*16, +16), k in [kk*32, +32):
//   Xs[f*512 + slot*8 + e], slot = (lane>>4)*16 + (lane&15)
//   = X[rowblk16*16 + (lane&15)][kk*32 + (lane>>4)*8 + e]
// One fragment = 1 KB, contiguous. A 128-row tile t = fragments [t*32, t*32+32).

__device__ __forceinline__ unsigned short f2bf(float f) {
    unsigned int u = __builtin_bit_cast(unsigned int, f);
    unsigned int r = (u + 0x7FFFu + ((u >> 16) & 1u)) >> 16;
    return (unsigned short)r;
}

__device__ __forceinline__ float bf2f(unsigned short u) {
    unsigned int x = ((unsigned int)u) << 16;
    return __builtin_bit_cast(float, x);
}

__device__ __forceinline__ void gload_lds16(const void* g, void* l) {
    __builtin_amdgcn_global_load_lds(
        (const __attribute__((address_space(1))) unsigned int*)g,
        (__attribute__((address_space(3))) unsigned int*)l, 16, 0, 0);
}

// 256 blocks x 256 threads; block handles 32 keypoints, thread handles 8 b's.
__global__ __launch_bounds__(256) void prep_kernel(
        const float* __restrict__ in, unsigned short* __restrict__ Xbf,
        float* __restrict__ sq) {
    int tid = threadIdx.x;
    int p = tid >> 5, idx = tid & 31;
    int n = blockIdx.x * 32 + idx;
    int t16 = n >> 4, l16 = n & 15;
    unsigned int* dst = (unsigned int*)Xbf;
    float s = 0.0f;
    #pragma unroll
    for (int q = 0; q < 8; ++q) {
        int b = p * 8 + q;
        float2 v = *(const float2*)(in + (size_t)b * (N_KP * 2) + n * 2);
        unsigned short h0 = f2bf(v.x);
        unsigned short h1 = f2bf(v.y);
        float f0 = bf2f(h0), f1 = bf2f(h1);
        s = fmaf(f0, f0, s);
        s = fmaf(f1, f1, s);
        unsigned int off_us = (((unsigned)(t16 * 4 + (b >> 4)) * 64
                                + ((b >> 2) & 3) * 16 + l16) << 3) + ((b & 3) << 1);
        dst[off_us >> 1] = ((unsigned int)h1 << 16) | h0;
    }
    __shared__ float wsq[256];
    wsq[tid] = s;
    __syncthreads();
    if (tid < 32) {
        float t = 0.0f;
        #pragma unroll
        for (int pp = 0; pp < 8; ++pp) t += wsq[pp * 32 + tid];
        sq[blockIdx.x * 32 + tid] = t;
    }
}

__global__ __launch_bounds__(256) void pair_kernel(
        const unsigned short* __restrict__ Xbf, const float* __restrict__ sq,
        float* __restrict__ partials) {
    int bid = blockIdx.x;
    int start = (bid * NTILES) >> 9;
    int end   = ((bid + 1) * NTILES) >> 9;
    int nsteps = end - start;

    // decode (ti, tj), ti <= tj, for linear index `start`.
    int ti = (int)((129.0f - sqrtf(129.0f * 129.0f - 8.0f * (float)start)) * 0.5f);
    while (ti > 0 && ti * (129 - ti) / 2 > start) --ti;
    while ((ti + 1) * (129 - (ti + 1)) / 2 <= start) ++ti;
    int tj = ti + (start - ti * (129 - ti) / 2);

    int wid  = threadIdx.x >> 6;
    int lane = threadIdx.x & 63;
    int wr = wid >> 1, wc = wid & 1;
    int l16 = lane & 15, lhi = lane >> 4;

    __shared__ __align__(16) unsigned short B_lds[2][32 * 512];  // 2 x 32 KB
    __shared__ float wsum[4];

    const bf16x8* Xs8 = (const bf16x8*)Xbf;   // fragment f at Xs8[f*64 + lane]

    // A row-panel fragments + si norms (reloaded only on row change)
    bf16x8 a[4][4];      // [m][kk]
    float si[4][4];      // [m][r]
    {
        #pragma unroll
        for (int m = 0; m < 4; ++m)
            #pragma unroll
            for (int kk = 0; kk < 4; ++kk)
                a[m][kk] = Xs8[(size_t)((ti * 8 + wr * 4 + m) * 4 + kk) * 64 + lane];
        #pragma unroll
        for (int m = 0; m < 4; ++m)
            #pragma unroll
            for (int r = 0; r < 4; ++r)
                si[m][r] = sq[ti * 128 + wr * 64 + m * 16 + lhi * 4 + r];
    }

    // prologue: stage first B tile into buf 0
    #pragma unroll
    for (int c0 = 0; c0 < 8; ++c0) {
        int c = wid * 8 + c0;
        gload_lds16((const char*)Xbf + ((size_t)(tj * 32 + c)) * 1024 + lane * 16,
                    (char*)B_lds[0] + (size_t)c * 1024);
    }
    __syncthreads();

    float run = 0.0f;
    int ndiag = 0;
    int cur = 0;
    int cti = ti, ctj = tj;

    for (int t = 0; t < nsteps; ++t) {
        // next tile coords
        int nti = cti, ntj = ctj + 1;
        if (ntj == NT) { ++nti; ntj = nti; }

        // phase 1: issue next-tile stage into the other buffer
        if (t + 1 < nsteps) {
            #pragma unroll
            for (int c0 = 0; c0 < 8; ++c0) {
                int c = wid * 8 + c0;
                gload_lds16((const char*)Xbf + ((size_t)(ntj * 32 + c)) * 1024 + lane * 16,
                            (char*)B_lds[cur ^ 1] + (size_t)c * 1024);
            }
        }

        // column norms for current tile (issued early, used in epilogue)
        float sqj[4];
        #pragma unroll
        for (int n = 0; n < 4; ++n) sqj[n] = sq[ctj * 128 + wc * 64 + n * 16 + l16];

        // phase 2: ds_read + MFMA from current buffer
        const bf16x8* L = (const bf16x8*)B_lds[cur];
        f32x4 acc[4][4] = {};
        #pragma unroll
        for (int kk = 0; kk < 4; ++kk) {
            bf16x8 b[4];
            #pragma unroll
            for (int n = 0; n < 4; ++n)
                b[n] = L[((wc * 4 + n) * 4 + kk) * 64 + lane];
            #pragma unroll
            for (int m = 0; m < 4; ++m)
                #pragma unroll
                for (int n = 0; n < 4; ++n)
                    acc[m][n] = __builtin_amdgcn_mfma_f32_16x16x32_bf16(
                        a[m][kk], b[n], acc[m][n], 0, 0, 0);
        }

        // epilogue: d2 = si + sqj - 2*dot; run += [2x] exp2(COEF2*sqrt(d2))
        float p0 = 0.0f, p1 = 0.0f, p2 = 0.0f, p3 = 0.0f;
        #pragma unroll
        for (int m = 0; m < 4; ++m) {
            #pragma unroll
            for (int n = 0; n < 4; ++n) {
                float base0 = si[m][0] + sqj[n];
                float base1 = si[m][1] + sqj[n];
                float base2 = si[m][2] + sqj[n];
                float base3 = si[m][3] + sqj[n];
                float d2_0 = fmaf(-2.0f, acc[m][n][0], base0);
                float d2_1 = fmaf(-2.0f, acc[m][n][1], base1);
                float d2_2 = fmaf(-2.0f, acc[m][n][2], base2);
                float d2_3 = fmaf(-2.0f, acc[m][n][3], base3);
                p0 += __builtin_amdgcn_exp2f(COEF2 * __builtin_amdgcn_sqrtf(fabsf(d2_0)));
                p1 += __builtin_amdgcn_exp2f(COEF2 * __builtin_amdgcn_sqrtf(fabsf(d2_1)));
                p2 += __builtin_amdgcn_exp2f(COEF2 * __builtin_amdgcn_sqrtf(fabsf(d2_2)));
                p3 += __builtin_amdgcn_exp2f(COEF2 * __builtin_amdgcn_sqrtf(fabsf(d2_3)));
            }
        }
        float s = (p0 + p1) + (p2 + p3);
        bool diag = (cti == ctj);
        run += diag ? s : 2.0f * s;
        ndiag += diag ? 1 : 0;

        // A/si reload if next step enters a new row panel (rare; block-uniform)
        if (t + 1 < nsteps && nti != cti) {
            #pragma unroll
            for (int m = 0; m < 4; ++m)
                #pragma unroll
                for (int kk = 0; kk < 4; ++kk)
                    a[m][kk] = Xs8[(size_t)((nti * 8 + wr * 4 + m) * 4 + kk) * 64 + lane];
            #pragma unroll
            for (int m = 0; m < 4; ++m)
                #pragma unroll
                for (int r = 0; r < 4; ++r)
                    si[m][r] = sq[nti * 128 + wr * 64 + m * 16 + lhi * 4 + r];
        }

        __syncthreads();   // stage(next) done + all waves done reading buf[cur]
        cur ^= 1;
        cti = nti; ctj = ntj;
    }

    // block reduction -> one partial
    #pragma unroll
    for (int m = 32; m; m >>= 1) run += __shfl_xor(run, m, 64);
    if (lane == 0) wsum[wid] = run;
    __syncthreads();
    if (threadIdx.x == 0) {
        float v = (wsum[0] + wsum[1]) + (wsum[2] + wsum[3]);
        partials[bid] = v - 128.0f * (float)ndiag;  // remove i==j terms (~1.0 each)
    }
}

__global__ __launch_bounds__(256) void reduce_kernel(
        const float* __restrict__ partials, float* __restrict__ out) {
    float s = 0.0f;
    for (int i = threadIdx.x; i < NBLK; i += 256) s += partials[i];
    #pragma unroll
    for (int m = 32; m; m >>= 1) s += __shfl_xor(s, m, 64);
    __shared__ float wsum[4];
    int wid = threadIdx.x >> 6, lane = threadIdx.x & 63;
    if (lane == 0) wsum[wid] = s;
    __syncthreads();
    if (threadIdx.x == 0) out[0] = (wsum[0] + wsum[1]) + (wsum[2] + wsum[3]);
}

extern "C" void kernel_launch(void* const* d_in, const int* in_sizes, int n_in,
                              void* d_out, int out_size, void* d_ws, size_t ws_size,
                              hipStream_t stream) {
    const float* in = (const float*)d_in[0];
    float* out = (float*)d_out;

    // workspace layout: Xs (2 MB) | sq (32 KB) | partials (NBLK*4 B)
    unsigned short* Xbf = (unsigned short*)d_ws;
    float* sq = (float*)((char*)d_ws + (size_t)N_KP * KDIM * 2);
    float* partials = (float*)((char*)d_ws + (size_t)N_KP * KDIM * 2
                               + (size_t)N_KP * 4);

    prep_kernel<<<N_KP / 32, 256, 0, stream>>>(in, Xbf, sq);
    pair_kernel<<<NBLK, 256, 0, stream>>>(Xbf, sq, partials);
    reduce_kernel<<<1, 256, 0, stream>>>(partials, out);
}

// Round 7
// 31.868 us; speedup vs baseline: 1.1795x; 1.1795x over previous
//
#include <hip/hip_runtime.h>
#include <hip/hip_bf16.h>

// loss_separation: X[n, b*2+c] = keypoints[b, n, c], N=8192 rows, K=128 cols.
// loss = sum_{i != j} exp(-0.4 * ||X_i - X_j||)
// Round 7: back to 2080 one-tile blocks (fine-grained balance), but stage
// ONLY the B tile in LDS (32 KB -> 4 blocks/CU, 4 waves/SIMD, vs 64 KB -> 2).
// A fragments read per-kk from global: whole Xs (2 MB) is L2-resident per XCD,
// and wave pairs share A addresses (L1 broadcast). __launch_bounds__(256,4)
// caps VGPR at 128 to guarantee the occupancy.

#define N_KP   8192
#define KDIM   128          // B*C = 64*2
#define NT     64           // number of 128-row tiles
#define NTILES (NT * (NT + 1) / 2)   // 2080 upper-tri tiles
#define COEF2  (-0.57707801635558535f)   // -0.4 * log2(e)

typedef __attribute__((ext_vector_type(8))) short bf16x8;
typedef __attribute__((ext_vector_type(4))) float f32x4;

// Swizzled X layout (ushort units): fragment f = (rowblk16*4 + kk) holds the
// MFMA A/B fragment for rows [rowblk16*16, +16), k in [kk*32, +32):
//   Xs[f*512 + slot*8 + e], slot = (lane>>4)*16 + (lane&15)
//   = X[rowblk16*16 + (lane&15)][kk*32 + (lane>>4)*8 + e]
// One fragment = 1 KB, contiguous. A 128-row tile t = fragments [t*32, t*32+32).

__device__ __forceinline__ unsigned short f2bf(float f) {
    unsigned int u = __builtin_bit_cast(unsigned int, f);
    unsigned int r = (u + 0x7FFFu + ((u >> 16) & 1u)) >> 16;
    return (unsigned short)r;
}

__device__ __forceinline__ float bf2f(unsigned short u) {
    unsigned int x = ((unsigned int)u) << 16;
    return __builtin_bit_cast(float, x);
}

__device__ __forceinline__ void gload_lds16(const void* g, void* l) {
    __builtin_amdgcn_global_load_lds(
        (const __attribute__((address_space(1))) unsigned int*)g,
        (__attribute__((address_space(3))) unsigned int*)l, 16, 0, 0);
}

// 256 blocks x 256 threads; block handles 32 keypoints, thread handles 8 b's.
__global__ __launch_bounds__(256) void prep_kernel(
        const float* __restrict__ in, unsigned short* __restrict__ Xbf,
        float* __restrict__ sq) {
    int tid = threadIdx.x;
    int p = tid >> 5, idx = tid & 31;
    int n = blockIdx.x * 32 + idx;
    int t16 = n >> 4, l16 = n & 15;
    unsigned int* dst = (unsigned int*)Xbf;
    float s = 0.0f;
    #pragma unroll
    for (int q = 0; q < 8; ++q) {
        int b = p * 8 + q;
        float2 v = *(const float2*)(in + (size_t)b * (N_KP * 2) + n * 2);
        unsigned short h0 = f2bf(v.x);
        unsigned short h1 = f2bf(v.y);
        float f0 = bf2f(h0), f1 = bf2f(h1);
        s = fmaf(f0, f0, s);
        s = fmaf(f1, f1, s);
        unsigned int off_us = (((unsigned)(t16 * 4 + (b >> 4)) * 64
                                + ((b >> 2) & 3) * 16 + l16) << 3) + ((b & 3) << 1);
        dst[off_us >> 1] = ((unsigned int)h1 << 16) | h0;
    }
    __shared__ float wsq[256];
    wsq[tid] = s;
    __syncthreads();
    if (tid < 32) {
        float t = 0.0f;
        #pragma unroll
        for (int pp = 0; pp < 8; ++pp) t += wsq[pp * 32 + tid];
        sq[blockIdx.x * 32 + tid] = t;
    }
}

__global__ __launch_bounds__(256, 4) void pair_kernel(
        const unsigned short* __restrict__ Xbf, const float* __restrict__ sq,
        float* __restrict__ partials) {
    int bid = blockIdx.x;
    // decode (ti, tj), ti <= tj: off(t) = t*(129-t)/2 tiles precede row t.
    int ti = (int)((129.0f - sqrtf(129.0f * 129.0f - 8.0f * (float)bid)) * 0.5f);
    while (ti > 0 && ti * (129 - ti) / 2 > bid) --ti;
    while ((ti + 1) * (129 - (ti + 1)) / 2 <= bid) ++ti;
    int tj = ti + (bid - ti * (129 - ti) / 2);

    int wid  = threadIdx.x >> 6;
    int lane = threadIdx.x & 63;
    int wr = wid >> 1, wc = wid & 1;
    int l16 = lane & 15, lhi = lane >> 4;

    __shared__ __align__(16) unsigned short B_lds[32 * 512];  // 32 KB
    __shared__ float wsum[4];

    // stage B tile: 32 x 1KB chunks; wave wid stages chunks [wid*8, wid*8+8)
    #pragma unroll
    for (int c0 = 0; c0 < 8; ++c0) {
        int c = wid * 8 + c0;
        gload_lds16((const char*)Xbf + ((size_t)(tj * 32 + c)) * 1024 + lane * 16,
                    (char*)B_lds + (size_t)c * 1024);
    }
    __syncthreads();

    const bf16x8* Xs8 = (const bf16x8*)Xbf;   // fragment f at Xs8[f*64 + lane]
    const bf16x8* L   = (const bf16x8*)B_lds;

    f32x4 acc[4][4] = {};
    #pragma unroll
    for (int kk = 0; kk < 4; ++kk) {
        bf16x8 a[4], b[4];
        #pragma unroll
        for (int m = 0; m < 4; ++m)   // A from global (L2-hot, coalesced 1KB)
            a[m] = Xs8[(size_t)((ti * 8 + wr * 4 + m) * 4 + kk) * 64 + lane];
        #pragma unroll
        for (int n = 0; n < 4; ++n)   // B from LDS (contiguous ds_read_b128)
            b[n] = L[((wc * 4 + n) * 4 + kk) * 64 + lane];
        #pragma unroll
        for (int m = 0; m < 4; ++m)
            #pragma unroll
            for (int n = 0; n < 4; ++n)
                acc[m][n] = __builtin_amdgcn_mfma_f32_16x16x32_bf16(
                    a[m], b[n], acc[m][n], 0, 0, 0);
    }

    int ibase = ti * 128 + wr * 64;
    int jbase = tj * 128 + wc * 64;

    // norms loaded after MFMA loop to keep peak VGPR under the 128 cap
    float si[4][4];
    #pragma unroll
    for (int m = 0; m < 4; ++m)
        #pragma unroll
        for (int r = 0; r < 4; ++r)
            si[m][r] = sq[ibase + m * 16 + lhi * 4 + r];
    float sqj[4];
    #pragma unroll
    for (int n = 0; n < 4; ++n) sqj[n] = sq[jbase + n * 16 + l16];

    float p0 = 0.0f, p1 = 0.0f, p2 = 0.0f, p3 = 0.0f;
    #pragma unroll
    for (int m = 0; m < 4; ++m) {
        #pragma unroll
        for (int n = 0; n < 4; ++n) {
            float d2_0 = fmaf(-2.0f, acc[m][n][0], si[m][0] + sqj[n]);
            float d2_1 = fmaf(-2.0f, acc[m][n][1], si[m][1] + sqj[n]);
            float d2_2 = fmaf(-2.0f, acc[m][n][2], si[m][2] + sqj[n]);
            float d2_3 = fmaf(-2.0f, acc[m][n][3], si[m][3] + sqj[n]);
            p0 += __builtin_amdgcn_exp2f(COEF2 * __builtin_amdgcn_sqrtf(fabsf(d2_0)));
            p1 += __builtin_amdgcn_exp2f(COEF2 * __builtin_amdgcn_sqrtf(fabsf(d2_1)));
            p2 += __builtin_amdgcn_exp2f(COEF2 * __builtin_amdgcn_sqrtf(fabsf(d2_2)));
            p3 += __builtin_amdgcn_exp2f(COEF2 * __builtin_amdgcn_sqrtf(fabsf(d2_3)));
        }
    }
    float partial = (p0 + p1) + (p2 + p3);

    #pragma unroll
    for (int m = 32; m; m >>= 1) partial += __shfl_xor(partial, m, 64);
    if (lane == 0) wsum[wid] = partial;
    __syncthreads();
    if (threadIdx.x == 0) {
        float v = (wsum[0] + wsum[1]) + (wsum[2] + wsum[3]);
        // diagonal tiles: remove the 128 i==j terms (each ~= exp(0) = 1).
        // off-diagonal tiles: mirror tile (tj, ti) not computed -> double.
        if (ti == tj) v -= 128.0f; else v *= 2.0f;
        partials[bid] = v;
    }
}

__global__ __launch_bounds__(256) void reduce_kernel(
        const float* __restrict__ partials, float* __restrict__ out) {
    float s = 0.0f;
    for (int i = threadIdx.x; i < NTILES; i += 256) s += partials[i];
    #pragma unroll
    for (int m = 32; m; m >>= 1) s += __shfl_xor(s, m, 64);
    __shared__ float wsum[4];
    int wid = threadIdx.x >> 6, lane = threadIdx.x & 63;
    if (lane == 0) wsum[wid] = s;
    __syncthreads();
    if (threadIdx.x == 0) out[0] = (wsum[0] + wsum[1]) + (wsum[2] + wsum[3]);
}

extern "C" void kernel_launch(void* const* d_in, const int* in_sizes, int n_in,
                              void* d_out, int out_size, void* d_ws, size_t ws_size,
                              hipStream_t stream) {
    const float* in = (const float*)d_in[0];
    float* out = (float*)d_out;

    // workspace layout: Xs (2 MB) | sq (32 KB) | partials (NTILES*4 B)
    unsigned short* Xbf = (unsigned short*)d_ws;
    float* sq = (float*)((char*)d_ws + (size_t)N_KP * KDIM * 2);
    float* partials = (float*)((char*)d_ws + (size_t)N_KP * KDIM * 2
                               + (size_t)N_KP * 4);

    prep_kernel<<<N_KP / 32, 256, 0, stream>>>(in, Xbf, sq);
    pair_kernel<<<NTILES, 256, 0, stream>>>(Xbf, sq, partials);
    reduce_kernel<<<1, 256, 0, stream>>>(partials, out);
}